// Round 1
// baseline (95.301 us; speedup 1.0000x reference)
//
#include <hip/hip_runtime.h>
#include <hip/hip_bf16.h>
#include <math.h>

// Problem: B=16, L=512, H=8, D=64, k_top=6.
// x_corr_mean[b,l] = (1/(H*L)) * sum_h (sum_d q[b,l,h,d]) * (sum_d k[b,l,h,d])
// (sum over all circular-correlation lags == product of sums; FFT eliminated)

#define B_  16
#define L_  512
#define H_  8
#define D_  64
#define HD_ 512          // H*D
#define KTOP 6
#define MEAN_SCALE (1.0f / 4096.0f)   // 1/(H*L)

__global__ __launch_bounds__(512) void corr_mean_kernel(
    const float* __restrict__ q, const float* __restrict__ k,
    float* __restrict__ corr) {
    const int bl = blockIdx.x;          // 0 .. B*L-1
    const int t  = threadIdx.x;         // 0 .. 511 ; wave (t>>6) == head
    const size_t base = (size_t)bl * HD_;
    float qv = q[base + t];
    float kv = k[base + t];
    // reduce each head's 64 lanes (one wave per head)
    #pragma unroll
    for (int off = 32; off >= 1; off >>= 1) {
        qv += __shfl_down(qv, off, 64);
        kv += __shfl_down(kv, off, 64);
    }
    __shared__ float prod[H_];
    const int wave = t >> 6;
    if ((t & 63) == 0) prod[wave] = qv * kv;
    __syncthreads();
    if (t == 0) {
        float s = 0.f;
        #pragma unroll
        for (int h = 0; h < H_; ++h) s += prod[h];
        corr[bl] = s * MEAN_SCALE;
    }
}

__global__ __launch_bounds__(512) void topk_agg_kernel(
    const float* __restrict__ corr, const float* __restrict__ v,
    float* __restrict__ out) {
    const int b = blockIdx.x;   // 0..15
    const int t = threadIdx.x;  // 0..511
    __shared__ float sval[L_];
    __shared__ float redv[8];
    __shared__ int   redi[8];
    __shared__ float topv[KTOP];
    __shared__ int   topi[KTOP];
    __shared__ float wgt[KTOP];

    sval[t] = corr[b * L_ + t];
    __syncthreads();

    // extract top-6 by repeated block-max
    for (int j = 0; j < KTOP; ++j) {
        float mv = sval[t];
        int   mi = t;
        #pragma unroll
        for (int off = 32; off >= 1; off >>= 1) {
            float ov = __shfl_down(mv, off, 64);
            int   oi = __shfl_down(mi, off, 64);
            if (ov > mv) { mv = ov; mi = oi; }
        }
        if ((t & 63) == 0) { redv[t >> 6] = mv; redi[t >> 6] = mi; }
        __syncthreads();
        if (t == 0) {
            float bm = redv[0]; int bi = redi[0];
            #pragma unroll
            for (int w = 1; w < 8; ++w)
                if (redv[w] > bm) { bm = redv[w]; bi = redi[w]; }
            topv[j] = bm; topi[j] = bi;
            sval[bi] = -INFINITY;   // remove for next round
        }
        __syncthreads();
    }

    // softmax over the 6 top values (topv[0] is the max)
    if (t == 0) {
        float m = topv[0];
        float e[KTOP]; float s = 0.f;
        #pragma unroll
        for (int j = 0; j < KTOP; ++j) { e[j] = expf(topv[j] - m); s += e[j]; }
        #pragma unroll
        for (int j = 0; j < KTOP; ++j) wgt[j] = e[j] / s;
    }
    __syncthreads();

    // out[b, h, d] = sum_j w[j] * values[b, idx_j, h, d];  t = h*64+d
    float acc = 0.f;
    #pragma unroll
    for (int j = 0; j < KTOP; ++j) {
        acc += wgt[j] * v[((size_t)b * L_ + topi[j]) * HD_ + t];
    }
    out[b * HD_ + t] = acc;
}

extern "C" void kernel_launch(void* const* d_in, const int* in_sizes, int n_in,
                              void* d_out, int out_size, void* d_ws, size_t ws_size,
                              hipStream_t stream) {
    const float* q = (const float*)d_in[0];
    const float* k = (const float*)d_in[1];
    const float* v = (const float*)d_in[2];
    float* out = (float*)d_out;
    float* corr = (float*)d_ws;   // B*L floats = 32 KB

    corr_mean_kernel<<<B_ * L_, 512, 0, stream>>>(q, k, corr);
    topk_agg_kernel<<<B_, 512, 0, stream>>>(corr, v, out);
}